// Round 17
// baseline (3744.204 us; speedup 1.0000x reference)
//
#include <hip/hip_runtime.h>
#include <hip/hip_cooperative_groups.h>

#define NN 50000
#define NE 800000
#define OUTC 176  // 11 * 16

namespace cg = cooperative_groups;

typedef unsigned int uint32;
typedef short bf16x8 __attribute__((ext_vector_type(8)));
typedef float f32x4 __attribute__((ext_vector_type(4)));
typedef unsigned int uint32x4 __attribute__((ext_vector_type(4)));

// ---------- bf16 helpers (manual, RNE) ----------
__device__ __forceinline__ uint32 f2bf_rne(float f) {
  union { float f; uint32 u; } v; v.f = f;
  uint32 u = v.u;
  return (u + 0x7FFFu + ((u >> 16) & 1u)) >> 16;
}
__device__ __forceinline__ uint32 packbf2(float a, float b) {
  return f2bf_rne(a) | (f2bf_rne(b) << 16);
}
__device__ __forceinline__ float blo(uint32 u) {
  union { uint32 x; float f; } t; t.x = u << 16; return t.f;
}
__device__ __forceinline__ float bhi(uint32 u) {
  union { uint32 x; float f; } t; t.x = u & 0xFFFF0000u; return t.f;
}
__device__ __forceinline__ float bf2f(unsigned short v) {
  union { uint32 x; float f; } t; t.x = ((uint32)v) << 16; return t.f;
}
__device__ __forceinline__ float sb2f(uint32 w, int b) {
  return (float)((int)(w << (24 - 8 * b)) >> 24);
}

// ---------- small kernels ----------
__global__ __launch_bounds__(256) void deg_count_kernel(const int* __restrict__ edst,
                                                        float* __restrict__ deg) {
  int e = blockIdx.x * 256 + threadIdx.x;
  if (e < NE) atomicAdd(&deg[edst[e]], 1.0f);
}

__global__ __launch_bounds__(256) void deg_inv_kernel(float* __restrict__ deg) {
  int n = blockIdx.x * 256 + threadIdx.x;
  if (n < NN) deg[n] = 1.0f / fmaxf(deg[n], 1.0f);
}

__global__ __launch_bounds__(256) void copy_col0_kernel(const float* __restrict__ hx,
                                                        float* __restrict__ out) {
  int n = blockIdx.x * 256 + threadIdx.x;
  if (n >= NN) return;
  const float4* s = reinterpret_cast<const float4*>(hx + (size_t)n * 16);
  float4* d = reinterpret_cast<float4*>(out + (size_t)n * OUTC);
  d[0] = s[0]; d[1] = s[1]; d[2] = s[2]; d[3] = s[3];
}

__global__ __launch_bounds__(256) void hx2hd_kernel(const float* __restrict__ hx,
                                                    unsigned short* __restrict__ hdb) {
  int t = blockIdx.x * 256 + threadIdx.x;
  if (t < NN * 16) hdb[t] = (unsigned short)f2bf_rne(hx[t]);
}

__global__ __launch_bounds__(256) void repack_w2_kernel(const float* __restrict__ w2,
                                                        float* __restrict__ w2t) {
  int i = blockIdx.x * 256 + threadIdx.x;
  if (i >= 256 * 1024) return;
  int d = i >> 10, r = i & 1023, k = r >> 4, c = r & 15;
  w2t[i] = w2[k * 256 + c * 16 + d];
}

__global__ __launch_bounds__(256) void repack_w2f_kernel(const float* __restrict__ w2,
                                                         unsigned short* __restrict__ w2f) {
  int i = blockIdx.x * 256 + threadIdx.x;  // 0..16383
  if (i >= 16384) return;
  int jj = i & 7;
  int l = (i >> 3) & 63;
  int nbm = i >> 9;
  int m = nbm & 1, nb = nbm >> 1;
  int k = m * 32 + (l >> 4) * 8 + jj;
  int j = nb * 16 + (l & 15);
  w2f[i] = (unsigned short)f2bf_rne(w2[k * 256 + j]);
}

// ---------- MFMA fnet: fused layer1 + 16x256x64 GEMM + int8 quantize ----------
__global__ __launch_bounds__(512) void fnet_mfma_i8_kernel(
    const float* __restrict__ ef, const float* __restrict__ w1, const float* __restrict__ b1,
    const unsigned short* __restrict__ w2f, const float* __restrict__ b2,
    unsigned char* __restrict__ W, unsigned short* __restrict__ S) {
  __shared__ float efs[1664];
  __shared__ short w2s[16384];
  const int wave = threadIdx.x >> 6;
  const int l = threadIdx.x & 63;
  const int wid = blockIdx.x * 8 + wave;
  const int d = l & 15, kg = l >> 4;

#pragma unroll
  for (int i = 0; i < 4; ++i)
    reinterpret_cast<uint4*>(w2s)[threadIdx.x + 512 * i] =
        reinterpret_cast<const uint4*>(w2f)[threadIdx.x + 512 * i];
  long long E0 = (long long)blockIdx.x * 128;
  if (threadIdx.x < 416) {
    reinterpret_cast<float4*>(efs)[threadIdx.x] =
        reinterpret_cast<const float4*>(ef + E0 * 13)[threadIdx.x];
  }
  __syncthreads();

  const int eloc = wave * 16 + d;
  float f[13];
#pragma unroll
  for (int i = 0; i < 13; ++i) f[i] = efs[eloc * 13 + i];
  float ua[8], ub[8];
#pragma unroll
  for (int j = 0; j < 8; ++j) { ua[j] = b1[kg * 8 + j]; ub[j] = b1[32 + kg * 8 + j]; }
#pragma unroll
  for (int i = 0; i < 13; ++i) {
    const float4* wa = reinterpret_cast<const float4*>(w1 + i * 64 + kg * 8);
    const float4* wb = reinterpret_cast<const float4*>(w1 + i * 64 + 32 + kg * 8);
    float4 a0 = wa[0], a1 = wa[1], c0 = wb[0], c1 = wb[1];
    float fi = f[i];
    ua[0] = fmaf(fi, a0.x, ua[0]); ua[1] = fmaf(fi, a0.y, ua[1]);
    ua[2] = fmaf(fi, a0.z, ua[2]); ua[3] = fmaf(fi, a0.w, ua[3]);
    ua[4] = fmaf(fi, a1.x, ua[4]); ua[5] = fmaf(fi, a1.y, ua[5]);
    ua[6] = fmaf(fi, a1.z, ua[6]); ua[7] = fmaf(fi, a1.w, ua[7]);
    ub[0] = fmaf(fi, c0.x, ub[0]); ub[1] = fmaf(fi, c0.y, ub[1]);
    ub[2] = fmaf(fi, c0.z, ub[2]); ub[3] = fmaf(fi, c0.w, ub[3]);
    ub[4] = fmaf(fi, c1.x, ub[4]); ub[5] = fmaf(fi, c1.y, ub[5]);
    ub[6] = fmaf(fi, c1.z, ub[6]); ub[7] = fmaf(fi, c1.w, ub[7]);
  }
  bf16x8 afrag0, afrag1;
#pragma unroll
  for (int j = 0; j < 8; ++j) {
    afrag0[j] = (short)f2bf_rne(fmaxf(ua[j], 0.0f));
    afrag1[j] = (short)f2bf_rne(fmaxf(ub[j], 0.0f));
  }

  float bias[16];
#pragma unroll
  for (int nb = 0; nb < 16; ++nb) bias[nb] = b2[nb * 16 + d];

  const bf16x8* Bp = reinterpret_cast<const bf16x8*>(w2s);
  f32x4 acc[16];
#pragma unroll
  for (int nb = 0; nb < 16; ++nb) {
    f32x4 c; c[0] = bias[nb]; c[1] = bias[nb]; c[2] = bias[nb]; c[3] = bias[nb];
    bf16x8 bf0 = Bp[(nb * 2 + 0) * 64 + l];
    bf16x8 bf1 = Bp[(nb * 2 + 1) * 64 + l];
    c = __builtin_amdgcn_mfma_f32_16x16x32_bf16(afrag0, bf0, c, 0, 0, 0);
    c = __builtin_amdgcn_mfma_f32_16x16x32_bf16(afrag1, bf1, c, 0, 0, 0);
    acc[nb] = c;
  }

  float mx[4];
#pragma unroll
  for (int r = 0; r < 4; ++r) {
    float m = 0.0f;
#pragma unroll
    for (int c = 0; c < 16; ++c) m = fmaxf(m, fabsf(acc[c][r]));
    mx[r] = m;
  }
#pragma unroll
  for (int mask = 1; mask < 16; mask <<= 1) {
#pragma unroll
    for (int r = 0; r < 4; ++r) mx[r] = fmaxf(mx[r], __shfl_xor(mx[r], mask));
  }
  uint32 sb[4]; float sinv[4];
#pragma unroll
  for (int r = 0; r < 4; ++r) {
    sb[r] = f2bf_rne(mx[r] * (1.0f / 127.0f));
    float sd = bf2f((unsigned short)sb[r]);
    sinv[r] = (sd > 0.0f) ? (1.0f / sd) : 0.0f;
  }
  if (d == 0) {
    uint32 lo = sb[0] | (sb[1] << 16), hi = sb[2] | (sb[3] << 16);
    *reinterpret_cast<uint2*>(S + (size_t)wid * 16 + kg * 4) = make_uint2(lo, hi);
  }

#pragma unroll
  for (int r = 0; r < 4; ++r) {
    size_t er = (size_t)wid * 16 + kg * 4 + r;
    uint32 p[4];
#pragma unroll
    for (int q = 0; q < 4; ++q) {
      uint32 wv = 0;
#pragma unroll
      for (int b = 0; b < 4; ++b) {
        float qf = fminf(127.0f, fmaxf(-127.0f, rintf(acc[q * 4 + b][r] * sinv[r])));
        wv |= ((uint32)((int)qf & 255)) << (8 * b);
      }
      p[q] = wv;
    }
    uint32x4 pv; pv[0] = p[0]; pv[1] = p[1]; pv[2] = p[2]; pv[3] = p[3];
    __builtin_nontemporal_store(pv,
        reinterpret_cast<uint32x4*>(W + (er << 8) + (d << 4)));
  }
}

// ---------- chunked-bf16 fallback fnet (plan 2) ----------
__device__ __forceinline__ void fnet_layer1(const float* __restrict__ ef, long long e,
                                            const float* __restrict__ w1,
                                            const float* __restrict__ b1,
                                            float* u) {
  float f[13];
#pragma unroll
  for (int i = 0; i < 13; ++i) f[i] = ef[(size_t)e * 13 + i];
#pragma unroll
  for (int k = 0; k < 64; ++k) u[k] = b1[k];
#pragma unroll
  for (int i = 0; i < 13; ++i) {
    float fi = f[i];
#pragma unroll
    for (int k = 0; k < 64; ++k) u[k] = fmaf(fi, w1[i * 64 + k], u[k]);
  }
#pragma unroll
  for (int k = 0; k < 64; ++k) u[k] = fmaxf(u[k], 0.0f);
}

__global__ __launch_bounds__(256) void fnet_bf16_kernel(
    const float* __restrict__ ef, const float* __restrict__ w1, const float* __restrict__ b1,
    const float* __restrict__ w2t, const float* __restrict__ b2,
    unsigned short* __restrict__ W, long long ebase, int ecnt) {
  int t = blockIdx.x * 256 + threadIdx.x;
  if (t >= ecnt) return;
  float u[64];
  fnet_layer1(ef, ebase + t, w1, b1, u);
#pragma unroll 1
  for (int dt = 0; dt < 8; ++dt) {
    uint32 p[16];
#pragma unroll
    for (int dd = 0; dd < 2; ++dd) {
      const int d = dt * 2 + dd;
      const float* wr = w2t + ((size_t)d << 10);
      float acc[16];
#pragma unroll
      for (int c = 0; c < 16; ++c) acc[c] = b2[c * 16 + d];
#pragma unroll
      for (int k = 0; k < 64; ++k) {
        float uk = u[k];
#pragma unroll
        for (int c = 0; c < 16; ++c) acc[c] = fmaf(uk, wr[k * 16 + c], acc[c]);
      }
#pragma unroll
      for (int q = 0; q < 8; ++q) p[dd * 8 + q] = packbf2(acc[2 * q], acc[2 * q + 1]);
    }
    uint4* dp = reinterpret_cast<uint4*>(W + ((size_t)t << 8) + (dt << 5));
    dp[0] = make_uint4(p[0], p[1], p[2], p[3]);
    dp[1] = make_uint4(p[4], p[5], p[6], p[7]);
    dp[2] = make_uint4(p[8], p[9], p[10], p[11]);
    dp[3] = make_uint4(p[12], p[13], p[14], p[15]);
  }
}

__global__ __launch_bounds__(256) void msg_bf16_kernel(
    const float* __restrict__ h, int h_ld,
    const unsigned short* __restrict__ W, long long ebase, int ecnt,
    const int* __restrict__ idxn, const int* __restrict__ edst,
    float* __restrict__ agg) {
  int t = blockIdx.x * 256 + threadIdx.x;
  if (t >= ecnt) return;
  int g = t >> 4, d = t & 15;
  int cur = -1;
  float acc = 0.0f;
  for (int s = 0; s < 16; ++s) {
    int erel = g * 16 + s;
    long long e = ebase + erel;
    int dst = edst[e];
    if (dst != cur) {
      if (cur >= 0) atomicAdd(&agg[(size_t)cur * 16 + d], acc);
      cur = dst; acc = 0.0f;
    }
    int src = idxn[e];
    const float4* hp = reinterpret_cast<const float4*>(h + (size_t)src * h_ld);
    float4 a0 = hp[0], a1 = hp[1], a2 = hp[2], a3 = hp[3];
    const uint4* wp = reinterpret_cast<const uint4*>(W + ((size_t)erel << 8) + (d << 4));
    uint4 w0 = wp[0], w1 = wp[1];
    acc = fmaf(a0.x, blo(w0.x), acc); acc = fmaf(a0.y, bhi(w0.x), acc);
    acc = fmaf(a0.z, blo(w0.y), acc); acc = fmaf(a0.w, bhi(w0.y), acc);
    acc = fmaf(a1.x, blo(w0.z), acc); acc = fmaf(a1.y, bhi(w0.z), acc);
    acc = fmaf(a1.z, blo(w0.w), acc); acc = fmaf(a1.w, bhi(w0.w), acc);
    acc = fmaf(a2.x, blo(w1.x), acc); acc = fmaf(a2.y, bhi(w1.x), acc);
    acc = fmaf(a2.z, blo(w1.y), acc); acc = fmaf(a2.w, bhi(w1.y), acc);
    acc = fmaf(a3.x, blo(w1.z), acc); acc = fmaf(a3.y, bhi(w1.z), acc);
    acc = fmaf(a3.z, blo(w1.w), acc); acc = fmaf(a3.w, bhi(w1.w), acc);
  }
  if (cur >= 0) atomicAdd(&agg[(size_t)cur * 16 + d], acc);
}

// ---------- shared device bodies for msg / cell ----------
__device__ __forceinline__ float edge_dot_i8bf(const uint32x4& h0, const uint32x4& h1,
                                               const uint32x4& wv) {
  float r = 0.0f;
  r = fmaf(blo(h0[0]), sb2f(wv[0], 0), r); r = fmaf(bhi(h0[0]), sb2f(wv[0], 1), r);
  r = fmaf(blo(h0[1]), sb2f(wv[0], 2), r); r = fmaf(bhi(h0[1]), sb2f(wv[0], 3), r);
  r = fmaf(blo(h0[2]), sb2f(wv[1], 0), r); r = fmaf(bhi(h0[2]), sb2f(wv[1], 1), r);
  r = fmaf(blo(h0[3]), sb2f(wv[1], 2), r); r = fmaf(bhi(h0[3]), sb2f(wv[1], 3), r);
  r = fmaf(blo(h1[0]), sb2f(wv[2], 0), r); r = fmaf(bhi(h1[0]), sb2f(wv[2], 1), r);
  r = fmaf(blo(h1[1]), sb2f(wv[2], 2), r); r = fmaf(bhi(h1[1]), sb2f(wv[2], 3), r);
  r = fmaf(blo(h1[2]), sb2f(wv[3], 0), r); r = fmaf(bhi(h1[2]), sb2f(wv[3], 1), r);
  r = fmaf(blo(h1[3]), sb2f(wv[3], 2), r); r = fmaf(bhi(h1[3]), sb2f(wv[3], 3), r);
  return r;
}

#define GET4(v, idx) ((idx) == 0 ? (v).x : (idx) == 1 ? (v).y : (idx) == 2 ? (v).z : (v).w)

__device__ __forceinline__ void msg_body(int t, const unsigned short* __restrict__ hdb,
                                         const unsigned char* __restrict__ W,
                                         const unsigned short* __restrict__ S,
                                         const int* __restrict__ idxn,
                                         const int* __restrict__ edst,
                                         float* __restrict__ agg) {
  const int g = t >> 4, d = t & 15;
  const int e0 = g * 32;

  int4 dv[8], sv[8];
  const int4* dp4 = reinterpret_cast<const int4*>(edst + e0);
  const int4* sp4 = reinterpret_cast<const int4*>(idxn + e0);
#pragma unroll
  for (int i = 0; i < 8; ++i) { dv[i] = dp4[i]; sv[i] = sp4[i]; }
  uint32x4 scv[4];
  const uint32x4* scp = reinterpret_cast<const uint32x4*>(S + e0);
#pragma unroll
  for (int i = 0; i < 4; ++i) scv[i] = scp[i];

  int curA = -1, curB = -1;
  float accA = 0.0f, accB = 0.0f;
#pragma unroll
  for (int s = 0; s < 16; ++s) {
    const int q = s >> 2, r4 = s & 3;
    int dstA = GET4(dv[q], r4),     srcA = GET4(sv[q], r4);
    int dstB = GET4(dv[4 + q], r4), srcB = GET4(sv[4 + q], r4);
    int eA = e0 + s, eB = e0 + 16 + s;
    const uint32x4* hpA = reinterpret_cast<const uint32x4*>(hdb + (size_t)srcA * 16);
    const uint32x4* hpB = reinterpret_cast<const uint32x4*>(hdb + (size_t)srcB * 16);
    uint32x4 ha0 = hpA[0], ha1 = hpA[1];
    uint32x4 hb0 = hpB[0], hb1 = hpB[1];
    uint32x4 wvA = *reinterpret_cast<const uint32x4*>(W + ((size_t)eA << 8) + (d << 4));
    uint32x4 wvB = *reinterpret_cast<const uint32x4*>(W + ((size_t)eB << 8) + (d << 4));
    uint32 swA = scv[s >> 3][(s >> 1) & 3];
    uint32 swB = scv[2 + (s >> 3)][(s >> 1) & 3];
    float scA = bf2f((unsigned short)((s & 1) ? (swA >> 16) : (swA & 0xFFFF)));
    float scB = bf2f((unsigned short)((s & 1) ? (swB >> 16) : (swB & 0xFFFF)));
    if (dstA != curA) {
      if (curA >= 0) atomicAdd(&agg[(size_t)curA * 16 + d], accA);
      curA = dstA; accA = 0.0f;
    }
    if (dstB != curB) {
      if (curB >= 0) atomicAdd(&agg[(size_t)curB * 16 + d], accB);
      curB = dstB; accB = 0.0f;
    }
    accA = fmaf(edge_dot_i8bf(ha0, ha1, wvA), scA, accA);
    accB = fmaf(edge_dot_i8bf(hb0, hb1, wvB), scB, accB);
  }
  atomicAdd(&agg[(size_t)curA * 16 + d], accA);
  atomicAdd(&agg[(size_t)curB * 16 + d], accB);
}

__device__ __forceinline__ void cell_body(
    int t, float* agg, const float* __restrict__ invd,
    const float* hin, int hin_ld,
    const float* __restrict__ wih, const float* __restrict__ whh,
    const float* __restrict__ bih, const float* __restrict__ bhh,
    float* hout, int hout_ld,
    const float* sprev, float* sout, int do_s,
    unsigned short* hdn, int wr_hd) {
  int n = t >> 4, j = t & 15;
  float inv = invd[n];
  float x[16], h[16];
  const float4* ap = reinterpret_cast<const float4*>(agg + (size_t)n * 16);
  const float4* hp = reinterpret_cast<const float4*>(hin + (size_t)n * hin_ld);
#pragma unroll
  for (int q = 0; q < 4; ++q) {
    float4 a = ap[q];
    x[4 * q + 0] = a.x * inv; x[4 * q + 1] = a.y * inv;
    x[4 * q + 2] = a.z * inv; x[4 * q + 3] = a.w * inv;
    float4 hv4 = hp[q];
    h[4 * q + 0] = hv4.x; h[4 * q + 1] = hv4.y;
    h[4 * q + 2] = hv4.z; h[4 * q + 3] = hv4.w;
  }
  const float4* wr4 = reinterpret_cast<const float4*>(wih + j * 16);
  const float4* wz4 = reinterpret_cast<const float4*>(wih + (16 + j) * 16);
  const float4* wn4 = reinterpret_cast<const float4*>(wih + (32 + j) * 16);
  const float4* vr4 = reinterpret_cast<const float4*>(whh + j * 16);
  const float4* vz4 = reinterpret_cast<const float4*>(whh + (16 + j) * 16);
  const float4* vn4 = reinterpret_cast<const float4*>(whh + (32 + j) * 16);
  float gr = bih[j], gz = bih[16 + j], gn = bih[32 + j];
  float hr = bhh[j], hz = bhh[16 + j], hn = bhh[32 + j];
#pragma unroll
  for (int q = 0; q < 4; ++q) {
    float4 wr = wr4[q], wz = wz4[q], wn = wn4[q];
    float4 vr = vr4[q], vz = vz4[q], vn = vn4[q];
    gr = fmaf(x[4 * q + 0], wr.x, gr); gr = fmaf(x[4 * q + 1], wr.y, gr);
    gr = fmaf(x[4 * q + 2], wr.z, gr); gr = fmaf(x[4 * q + 3], wr.w, gr);
    gz = fmaf(x[4 * q + 0], wz.x, gz); gz = fmaf(x[4 * q + 1], wz.y, gz);
    gz = fmaf(x[4 * q + 2], wz.z, gz); gz = fmaf(x[4 * q + 3], wz.w, gz);
    gn = fmaf(x[4 * q + 0], wn.x, gn); gn = fmaf(x[4 * q + 1], wn.y, gn);
    gn = fmaf(x[4 * q + 2], wn.z, gn); gn = fmaf(x[4 * q + 3], wn.w, gn);
    hr = fmaf(h[4 * q + 0], vr.x, hr); hr = fmaf(h[4 * q + 1], vr.y, hr);
    hr = fmaf(h[4 * q + 2], vr.z, hr); hr = fmaf(h[4 * q + 3], vr.w, hr);
    hz = fmaf(h[4 * q + 0], vz.x, hz); hz = fmaf(h[4 * q + 1], vz.y, hz);
    hz = fmaf(h[4 * q + 2], vz.z, hz); hz = fmaf(h[4 * q + 3], vz.w, hz);
    hn = fmaf(h[4 * q + 0], vn.x, hn); hn = fmaf(h[4 * q + 1], vn.y, hn);
    hn = fmaf(h[4 * q + 2], vn.z, hn); hn = fmaf(h[4 * q + 3], vn.w, hn);
  }
  float r = 1.0f / (1.0f + expf(-(gr + hr)));
  float z = 1.0f / (1.0f + expf(-(gz + hz)));
  float nng = tanhf(gn + r * hn);
  float hv = (1.0f - z) * nng + z * h[j];

  float svv = 0.0f;
  if (do_s) svv = hv + sprev[(size_t)n * OUTC + j];
  hout[(size_t)n * hout_ld + j] = hv;
  if (do_s) sout[(size_t)n * OUTC + j] = svv;
  if (wr_hd) hdn[(size_t)n * 16 + j] = (unsigned short)f2bf_rne(do_s ? svv : hv);

  asm volatile("" ::: "memory");
  agg[(size_t)n * 16 + j] = 0.0f;  // re-zero for next step
}

// ---------- standalone fallback kernels (non-cooperative path) ----------
__global__ __launch_bounds__(256) void msg_i8_kernel(
    const unsigned short* __restrict__ hdb,
    const unsigned char* __restrict__ W, const unsigned short* __restrict__ S,
    const int* __restrict__ idxn, const int* __restrict__ edst,
    float* __restrict__ agg) {
  int t = blockIdx.x * 256 + threadIdx.x;
  if (t < NE / 2) msg_body(t, hdb, W, S, idxn, edst, agg);
}

__global__ __launch_bounds__(256) void cell_kernel(
    float* agg, const float* __restrict__ invd,
    const float* hin, int hin_ld,
    const float* __restrict__ wih, const float* __restrict__ whh,
    const float* __restrict__ bih, const float* __restrict__ bhh,
    float* hout, int hout_ld,
    const float* sprev, float* sout, int do_s,
    unsigned short* hdn, int wr_hd) {
  int t = blockIdx.x * 256 + threadIdx.x;
  if (t < NN * 16)
    cell_body(t, agg, invd, hin, hin_ld, wih, whh, bih, bhh,
              hout, hout_ld, sprev, sout, do_s, hdn, wr_hd);
}

// ---------- persistent cooperative loop: 10x (msg ; sync ; cell ; sync) ----------
struct Step {
  const float* hin;
  float* hout;
  const float* sprev;
  float* sout;
  int hin_ld, hout_ld, do_s, wr_hd;
};

struct LoopP {
  unsigned short* hdb;
  const unsigned char* W;
  const unsigned short* S;
  const int* idxn;
  const int* edst;
  float* agg;
  const float* invd;
  const float* wih; const float* whh; const float* bih; const float* bhh;
  Step st[10];
};

__global__ __launch_bounds__(256, 4) void loop_kernel(LoopP P) {
  cg::grid_group grid = cg::this_grid();
  const int gsz = gridDim.x * 256;
  const int tid0 = blockIdx.x * 256 + threadIdx.x;
#pragma unroll 1
  for (int stp = 0; stp < 10; ++stp) {
#pragma unroll 1
    for (int t = tid0; t < NE / 2; t += gsz)
      msg_body(t, P.hdb, P.W, P.S, P.idxn, P.edst, P.agg);
    grid.sync();
    Step s = P.st[stp];
#pragma unroll 1
    for (int t = tid0; t < NN * 16; t += gsz)
      cell_body(t, P.agg, P.invd, s.hin, s.hin_ld, P.wih, P.whh, P.bih, P.bhh,
                s.hout, s.hout_ld, s.sprev, s.sout, s.do_s, P.hdb, s.wr_hd);
    grid.sync();
  }
}

extern "C" void kernel_launch(void* const* d_in, const int* in_sizes, int n_in,
                              void* d_out, int out_size, void* d_ws, size_t ws_size,
                              hipStream_t stream) {
  const float* hx   = (const float*)d_in[0];
  const float* ef   = (const float*)d_in[1];
  const int*   idxn = (const int*)d_in[2];
  const int*   edst = (const int*)d_in[3];
  const float* w1   = (const float*)d_in[4];
  const float* b1   = (const float*)d_in[5];
  const float* w2   = (const float*)d_in[6];
  const float* b2   = (const float*)d_in[7];
  const float* wih  = (const float*)d_in[8];
  const float* whh  = (const float*)d_in[9];
  const float* bih  = (const float*)d_in[10];
  const float* bhh  = (const float*)d_in[11];
  float* out = (float*)d_out;

  // workspace: invd | agg | w2f/w2t | hdb (bf16 dense h) | W | S
  const size_t INV_OFF = 0;
  const size_t AGG_OFF = 200064;
  const size_t W2T_OFF = 3400192;
  const size_t HD_OFF  = W2T_OFF + 1048576;
  const size_t W_OFF   = HD_OFF + (size_t)NN * 32;
  if (ws_size < W_OFF + 1600 * 512) return;
  char* wsb = (char*)d_ws;
  float* invd = (float*)(wsb + INV_OFF);
  float* agg  = (float*)(wsb + AGG_OFF);
  float* w2t  = (float*)(wsb + W2T_OFF);
  unsigned short* w2f = (unsigned short*)(wsb + W2T_OFF);
  unsigned short* hdb = (unsigned short*)(wsb + HD_OFF);
  unsigned short* W16 = (unsigned short*)(wsb + W_OFF);
  unsigned char*  W8  = (unsigned char*)(wsb + W_OFF);
  unsigned short* S16 = (unsigned short*)(wsb + W_OFF + (size_t)NE * 256);
  size_t wrem = ws_size - W_OFF;

  int plan;       // 1 = int8 + MFMA fnet, 2 = chunked bf16
  size_t chunk = NE;
  if (wrem >= (size_t)NE * 260) plan = 1;
  else {
    plan = 2;
    chunk = (wrem / 512) & ~(size_t)15;
    if (chunk > NE) chunk = NE;
  }

  const int NB  = (NN + 255) / 256;
  const int EB  = (NE + 255) / 256;
  const int MB  = (NE / 2 + 255) / 256;
  const int CB  = (NN * 16 + 255) / 256;

  hipMemsetAsync(invd, 0, (size_t)NN * 4, stream);
  hipMemsetAsync(agg, 0, (size_t)NN * 64, stream);
  deg_count_kernel<<<EB, 256, 0, stream>>>(edst, invd);
  deg_inv_kernel<<<NB, 256, 0, stream>>>(invd);
  copy_col0_kernel<<<NB, 256, 0, stream>>>(hx, out);
  hx2hd_kernel<<<CB, 256, 0, stream>>>(hx, hdb);

  auto col = [&](int c) { return out + (size_t)c * 16; };

  if (plan == 1) {
    repack_w2f_kernel<<<64, 256, 0, stream>>>(w2, w2f);
    fnet_mfma_i8_kernel<<<6250, 512, 0, stream>>>(ef, w1, b1, w2f, b2, W8, S16);

    // step table: cols 0..10 = [hx,h1,h2,s1,h4,s2,h6,s3,h8,s4,h10];
    // col10 = rotating stash for h3/h5/h7/h9.
    LoopP P;
    P.hdb = hdb; P.W = W8; P.S = S16; P.idxn = idxn; P.edst = edst;
    P.agg = agg; P.invd = invd; P.wih = wih; P.whh = whh; P.bih = bih; P.bhh = bhh;
    auto setst = [&](int i, const float* hin, int hin_ld, float* hout,
                     const float* sprev, float* sout, int wr_hd) {
      P.st[i].hin = hin; P.st[i].hin_ld = hin_ld;
      P.st[i].hout = hout; P.st[i].hout_ld = OUTC;
      P.st[i].sprev = sprev; P.st[i].sout = sout;
      P.st[i].do_s = (sprev != nullptr); P.st[i].wr_hd = wr_hd;
    };
    setst(0, hx,      16,  col(1),  nullptr, nullptr, 1);
    setst(1, col(1), OUTC, col(2),  nullptr, nullptr, 1);
    setst(2, col(2), OUTC, col(10), col(1),  col(3),  1);
    setst(3, col(3), OUTC, col(4),  nullptr, nullptr, 1);
    setst(4, col(4), OUTC, col(10), col(10), col(5),  1);
    setst(5, col(5), OUTC, col(6),  nullptr, nullptr, 1);
    setst(6, col(6), OUTC, col(10), col(10), col(7),  1);
    setst(7, col(7), OUTC, col(8),  nullptr, nullptr, 1);
    setst(8, col(8), OUTC, col(10), col(10), col(9),  1);
    setst(9, col(9), OUTC, col(10), nullptr, nullptr, 0);

    void* ka[] = { &P };
    hipError_t err = hipLaunchCooperativeKernel(
        reinterpret_cast<void*>(loop_kernel), dim3(1024), dim3(256), ka, 0, stream);
    if (err != hipSuccess) {
      // fallback: per-step dispatches
      for (int i = 0; i < 10; ++i) {
        msg_i8_kernel<<<MB, 256, 0, stream>>>(hdb, W8, S16, idxn, edst, agg);
        cell_kernel<<<CB, 256, 0, stream>>>(agg, invd, P.st[i].hin, P.st[i].hin_ld,
                                            wih, whh, bih, bhh,
                                            P.st[i].hout, OUTC, P.st[i].sprev,
                                            P.st[i].sout, P.st[i].do_s, hdb,
                                            P.st[i].wr_hd);
      }
    }
  } else {
    repack_w2_kernel<<<1024, 256, 0, stream>>>(w2, w2t);
    struct HStep { const float* hin; int ld; float* hout; const float* sp; float* so; int wr; };
    HStep hs[10] = {
      {hx, 16, col(1), nullptr, nullptr, 1},
      {col(1), OUTC, col(2), nullptr, nullptr, 1},
      {col(2), OUTC, col(10), col(1), col(3), 1},
      {col(3), OUTC, col(4), nullptr, nullptr, 1},
      {col(4), OUTC, col(10), col(10), col(5), 1},
      {col(5), OUTC, col(6), nullptr, nullptr, 1},
      {col(6), OUTC, col(10), col(10), col(7), 1},
      {col(7), OUTC, col(8), nullptr, nullptr, 1},
      {col(8), OUTC, col(10), col(10), col(9), 1},
      {col(9), OUTC, col(10), nullptr, nullptr, 0},
    };
    for (int i = 0; i < 10; ++i) {
      hipMemsetAsync(agg, 0, (size_t)NN * 64, stream);
      for (size_t e0 = 0; e0 < NE; e0 += chunk) {
        int cnt = (int)(((size_t)NE - e0) < chunk ? ((size_t)NE - e0) : chunk);
        fnet_bf16_kernel<<<(cnt + 255) / 256, 256, 0, stream>>>(ef, w1, b1, w2t, b2, W16,
                                                                (long long)e0, cnt);
        msg_bf16_kernel<<<(cnt + 255) / 256, 256, 0, stream>>>(hs[i].hin, hs[i].ld, W16,
                                                               (long long)e0, cnt,
                                                               idxn, edst, agg);
      }
      cell_kernel<<<CB, 256, 0, stream>>>(agg, invd, hs[i].hin, hs[i].ld,
                                          wih, whh, bih, bhh, hs[i].hout, OUTC,
                                          hs[i].sp, hs[i].so, hs[i].sp != nullptr,
                                          hdb, hs[i].wr);
    }
  }
}

// Round 18
// 885.285 us; speedup vs baseline: 4.2294x; 4.2294x over previous
//
#include <hip/hip_runtime.h>

#define NN 50000
#define NE 800000
#define OUTC 176  // 11 * 16

typedef unsigned int uint32;
typedef short bf16x8 __attribute__((ext_vector_type(8)));
typedef float f32x4 __attribute__((ext_vector_type(4)));
typedef unsigned int uint32x4 __attribute__((ext_vector_type(4)));

// ---------- bf16 helpers (manual, RNE) ----------
__device__ __forceinline__ uint32 f2bf_rne(float f) {
  union { float f; uint32 u; } v; v.f = f;
  uint32 u = v.u;
  return (u + 0x7FFFu + ((u >> 16) & 1u)) >> 16;
}
__device__ __forceinline__ uint32 packbf2(float a, float b) {
  return f2bf_rne(a) | (f2bf_rne(b) << 16);
}
__device__ __forceinline__ float blo(uint32 u) {
  union { uint32 x; float f; } t; t.x = u << 16; return t.f;
}
__device__ __forceinline__ float bhi(uint32 u) {
  union { uint32 x; float f; } t; t.x = u & 0xFFFF0000u; return t.f;
}
__device__ __forceinline__ float bf2f(unsigned short v) {
  union { uint32 x; float f; } t; t.x = ((uint32)v) << 16; return t.f;
}
__device__ __forceinline__ float sb2f(uint32 w, int b) {
  return (float)((int)(w << (24 - 8 * b)) >> 24);
}

// ---------- small kernels ----------
__global__ __launch_bounds__(256) void deg_count_kernel(const int* __restrict__ edst,
                                                        float* __restrict__ deg) {
  int e = blockIdx.x * 256 + threadIdx.x;
  if (e < NE) atomicAdd(&deg[edst[e]], 1.0f);
}

__global__ __launch_bounds__(256) void deg_inv_kernel(float* __restrict__ deg) {
  int n = blockIdx.x * 256 + threadIdx.x;
  if (n < NN) deg[n] = 1.0f / fmaxf(deg[n], 1.0f);
}

__global__ __launch_bounds__(256) void copy_col0_kernel(const float* __restrict__ hx,
                                                        float* __restrict__ out) {
  int n = blockIdx.x * 256 + threadIdx.x;
  if (n >= NN) return;
  const float4* s = reinterpret_cast<const float4*>(hx + (size_t)n * 16);
  float4* d = reinterpret_cast<float4*>(out + (size_t)n * OUTC);
  d[0] = s[0]; d[1] = s[1]; d[2] = s[2]; d[3] = s[3];
}

__global__ __launch_bounds__(256) void hx2hd_kernel(const float* __restrict__ hx,
                                                    unsigned short* __restrict__ hdb) {
  int t = blockIdx.x * 256 + threadIdx.x;
  if (t < NN * 16) hdb[t] = (unsigned short)f2bf_rne(hx[t]);
}

__global__ __launch_bounds__(256) void repack_w2_kernel(const float* __restrict__ w2,
                                                        float* __restrict__ w2t) {
  int i = blockIdx.x * 256 + threadIdx.x;
  if (i >= 256 * 1024) return;
  int d = i >> 10, r = i & 1023, k = r >> 4, c = r & 15;
  w2t[i] = w2[k * 256 + c * 16 + d];
}

__global__ __launch_bounds__(256) void repack_w2f_kernel(const float* __restrict__ w2,
                                                         unsigned short* __restrict__ w2f) {
  int i = blockIdx.x * 256 + threadIdx.x;  // 0..16383
  if (i >= 16384) return;
  int jj = i & 7;
  int l = (i >> 3) & 63;
  int nbm = i >> 9;
  int m = nbm & 1, nb = nbm >> 1;
  int k = m * 32 + (l >> 4) * 8 + jj;
  int j = nb * 16 + (l & 15);
  w2f[i] = (unsigned short)f2bf_rne(w2[k * 256 + j]);
}

// ---------- MFMA fnet: fused layer1 + 16x256x64 GEMM + int8 quantize ----------
// 1024-thread blocks: 16 waves share one 32KB w2s copy; wave cap -> 2 blocks/CU
// = 32 waves/CU (100%) vs R16's 45%. fnet was issue/latency-bound (VALU 54%).
__global__ __launch_bounds__(1024) void fnet_mfma_i8_kernel(
    const float* __restrict__ ef, const float* __restrict__ w1, const float* __restrict__ b1,
    const unsigned short* __restrict__ w2f, const float* __restrict__ b2,
    unsigned char* __restrict__ W, unsigned short* __restrict__ S) {
  __shared__ float efs[3328];         // 256 edges x 13 feats
  __shared__ short w2s[16384];        // full B fragments, 32KB
  const int wave = threadIdx.x >> 6;  // 0..15
  const int l = threadIdx.x & 63;
  const int wid = blockIdx.x * 16 + wave;
  const int d = l & 15, kg = l >> 4;

#pragma unroll
  for (int i = 0; i < 2; ++i)
    reinterpret_cast<uint4*>(w2s)[threadIdx.x + 1024 * i] =
        reinterpret_cast<const uint4*>(w2f)[threadIdx.x + 1024 * i];
  long long E0 = (long long)blockIdx.x * 256;
  if (threadIdx.x < 832) {
    reinterpret_cast<float4*>(efs)[threadIdx.x] =
        reinterpret_cast<const float4*>(ef + E0 * 13)[threadIdx.x];
  }
  __syncthreads();

  const int eloc = wave * 16 + d;
  float f[13];
#pragma unroll
  for (int i = 0; i < 13; ++i) f[i] = efs[eloc * 13 + i];
  float ua[8], ub[8];
#pragma unroll
  for (int j = 0; j < 8; ++j) { ua[j] = b1[kg * 8 + j]; ub[j] = b1[32 + kg * 8 + j]; }
#pragma unroll
  for (int i = 0; i < 13; ++i) {
    const float4* wa = reinterpret_cast<const float4*>(w1 + i * 64 + kg * 8);
    const float4* wb = reinterpret_cast<const float4*>(w1 + i * 64 + 32 + kg * 8);
    float4 a0 = wa[0], a1 = wa[1], c0 = wb[0], c1 = wb[1];
    float fi = f[i];
    ua[0] = fmaf(fi, a0.x, ua[0]); ua[1] = fmaf(fi, a0.y, ua[1]);
    ua[2] = fmaf(fi, a0.z, ua[2]); ua[3] = fmaf(fi, a0.w, ua[3]);
    ua[4] = fmaf(fi, a1.x, ua[4]); ua[5] = fmaf(fi, a1.y, ua[5]);
    ua[6] = fmaf(fi, a1.z, ua[6]); ua[7] = fmaf(fi, a1.w, ua[7]);
    ub[0] = fmaf(fi, c0.x, ub[0]); ub[1] = fmaf(fi, c0.y, ub[1]);
    ub[2] = fmaf(fi, c0.z, ub[2]); ub[3] = fmaf(fi, c0.w, ub[3]);
    ub[4] = fmaf(fi, c1.x, ub[4]); ub[5] = fmaf(fi, c1.y, ub[5]);
    ub[6] = fmaf(fi, c1.z, ub[6]); ub[7] = fmaf(fi, c1.w, ub[7]);
  }
  bf16x8 afrag0, afrag1;
#pragma unroll
  for (int j = 0; j < 8; ++j) {
    afrag0[j] = (short)f2bf_rne(fmaxf(ua[j], 0.0f));
    afrag1[j] = (short)f2bf_rne(fmaxf(ub[j], 0.0f));
  }

  float bias[16];
#pragma unroll
  for (int nb = 0; nb < 16; ++nb) bias[nb] = b2[nb * 16 + d];

  const bf16x8* Bp = reinterpret_cast<const bf16x8*>(w2s);
  f32x4 acc[16];
#pragma unroll
  for (int nb = 0; nb < 16; ++nb) {
    f32x4 c; c[0] = bias[nb]; c[1] = bias[nb]; c[2] = bias[nb]; c[3] = bias[nb];
    bf16x8 bf0 = Bp[(nb * 2 + 0) * 64 + l];
    bf16x8 bf1 = Bp[(nb * 2 + 1) * 64 + l];
    c = __builtin_amdgcn_mfma_f32_16x16x32_bf16(afrag0, bf0, c, 0, 0, 0);
    c = __builtin_amdgcn_mfma_f32_16x16x32_bf16(afrag1, bf1, c, 0, 0, 0);
    acc[nb] = c;
  }

  float mx[4];
#pragma unroll
  for (int r = 0; r < 4; ++r) {
    float m = 0.0f;
#pragma unroll
    for (int c = 0; c < 16; ++c) m = fmaxf(m, fabsf(acc[c][r]));
    mx[r] = m;
  }
#pragma unroll
  for (int mask = 1; mask < 16; mask <<= 1) {
#pragma unroll
    for (int r = 0; r < 4; ++r) mx[r] = fmaxf(mx[r], __shfl_xor(mx[r], mask));
  }
  uint32 sb[4]; float sinv[4];
#pragma unroll
  for (int r = 0; r < 4; ++r) {
    sb[r] = f2bf_rne(mx[r] * (1.0f / 127.0f));
    float sd = bf2f((unsigned short)sb[r]);
    sinv[r] = (sd > 0.0f) ? (1.0f / sd) : 0.0f;
  }
  if (d == 0) {
    uint32 lo = sb[0] | (sb[1] << 16), hi = sb[2] | (sb[3] << 16);
    *reinterpret_cast<uint2*>(S + (size_t)wid * 16 + kg * 4) = make_uint2(lo, hi);
  }

#pragma unroll
  for (int r = 0; r < 4; ++r) {
    size_t er = (size_t)wid * 16 + kg * 4 + r;
    uint32 p[4];
#pragma unroll
    for (int q = 0; q < 4; ++q) {
      uint32 wv = 0;
#pragma unroll
      for (int b = 0; b < 4; ++b) {
        float qf = fminf(127.0f, fmaxf(-127.0f, rintf(acc[q * 4 + b][r] * sinv[r])));
        wv |= ((uint32)((int)qf & 255)) << (8 * b);
      }
      p[q] = wv;
    }
    *reinterpret_cast<uint4*>(W + (er << 8) + (d << 4)) = make_uint4(p[0], p[1], p[2], p[3]);
  }
}

// ---------- chunked-bf16 fallback fnet (plan 2) ----------
__device__ __forceinline__ void fnet_layer1(const float* __restrict__ ef, long long e,
                                            const float* __restrict__ w1,
                                            const float* __restrict__ b1,
                                            float* u) {
  float f[13];
#pragma unroll
  for (int i = 0; i < 13; ++i) f[i] = ef[(size_t)e * 13 + i];
#pragma unroll
  for (int k = 0; k < 64; ++k) u[k] = b1[k];
#pragma unroll
  for (int i = 0; i < 13; ++i) {
    float fi = f[i];
#pragma unroll
    for (int k = 0; k < 64; ++k) u[k] = fmaf(fi, w1[i * 64 + k], u[k]);
  }
#pragma unroll
  for (int k = 0; k < 64; ++k) u[k] = fmaxf(u[k], 0.0f);
}

__global__ __launch_bounds__(256) void fnet_bf16_kernel(
    const float* __restrict__ ef, const float* __restrict__ w1, const float* __restrict__ b1,
    const float* __restrict__ w2t, const float* __restrict__ b2,
    unsigned short* __restrict__ W, long long ebase, int ecnt) {
  int t = blockIdx.x * 256 + threadIdx.x;
  if (t >= ecnt) return;
  float u[64];
  fnet_layer1(ef, ebase + t, w1, b1, u);
#pragma unroll 1
  for (int dt = 0; dt < 8; ++dt) {
    uint32 p[16];
#pragma unroll
    for (int dd = 0; dd < 2; ++dd) {
      const int d = dt * 2 + dd;
      const float* wr = w2t + ((size_t)d << 10);
      float acc[16];
#pragma unroll
      for (int c = 0; c < 16; ++c) acc[c] = b2[c * 16 + d];
#pragma unroll
      for (int k = 0; k < 64; ++k) {
        float uk = u[k];
#pragma unroll
        for (int c = 0; c < 16; ++c) acc[c] = fmaf(uk, wr[k * 16 + c], acc[c]);
      }
#pragma unroll
      for (int q = 0; q < 8; ++q) p[dd * 8 + q] = packbf2(acc[2 * q], acc[2 * q + 1]);
    }
    uint4* dp = reinterpret_cast<uint4*>(W + ((size_t)t << 8) + (dt << 5));
    dp[0] = make_uint4(p[0], p[1], p[2], p[3]);
    dp[1] = make_uint4(p[4], p[5], p[6], p[7]);
    dp[2] = make_uint4(p[8], p[9], p[10], p[11]);
    dp[3] = make_uint4(p[12], p[13], p[14], p[15]);
  }
}

__global__ __launch_bounds__(256) void msg_bf16_kernel(
    const float* __restrict__ h, int h_ld,
    const unsigned short* __restrict__ W, long long ebase, int ecnt,
    const int* __restrict__ idxn, const int* __restrict__ edst,
    float* __restrict__ agg) {
  int t = blockIdx.x * 256 + threadIdx.x;
  if (t >= ecnt) return;
  int g = t >> 4, d = t & 15;
  int cur = -1;
  float acc = 0.0f;
  for (int s = 0; s < 16; ++s) {
    int erel = g * 16 + s;
    long long e = ebase + erel;
    int dst = edst[e];
    if (dst != cur) {
      if (cur >= 0) atomicAdd(&agg[(size_t)cur * 16 + d], acc);
      cur = dst; acc = 0.0f;
    }
    int src = idxn[e];
    const float4* hp = reinterpret_cast<const float4*>(h + (size_t)src * h_ld);
    float4 a0 = hp[0], a1 = hp[1], a2 = hp[2], a3 = hp[3];
    const uint4* wp = reinterpret_cast<const uint4*>(W + ((size_t)erel << 8) + (d << 4));
    uint4 w0 = wp[0], w1 = wp[1];
    acc = fmaf(a0.x, blo(w0.x), acc); acc = fmaf(a0.y, bhi(w0.x), acc);
    acc = fmaf(a0.z, blo(w0.y), acc); acc = fmaf(a0.w, bhi(w0.y), acc);
    acc = fmaf(a1.x, blo(w0.z), acc); acc = fmaf(a1.y, bhi(w0.z), acc);
    acc = fmaf(a1.z, blo(w0.w), acc); acc = fmaf(a1.w, bhi(w0.w), acc);
    acc = fmaf(a2.x, blo(w1.x), acc); acc = fmaf(a2.y, bhi(w1.x), acc);
    acc = fmaf(a2.z, blo(w1.y), acc); acc = fmaf(a2.w, bhi(w1.y), acc);
    acc = fmaf(a3.x, blo(w1.z), acc); acc = fmaf(a3.y, bhi(w1.z), acc);
    acc = fmaf(a3.z, blo(w1.w), acc); acc = fmaf(a3.w, bhi(w1.w), acc);
  }
  if (cur >= 0) atomicAdd(&agg[(size_t)cur * 16 + d], acc);
}

// int8 W x bf16 h (L2-resident hdb). 16 lanes per 32-edge group (2 strips).
// edst/idxn/S for the whole group vector-preloaded upfront.
__device__ __forceinline__ float edge_dot_i8bf(const uint32x4& h0, const uint32x4& h1,
                                               const uint32x4& wv) {
  float r = 0.0f;
  r = fmaf(blo(h0[0]), sb2f(wv[0], 0), r); r = fmaf(bhi(h0[0]), sb2f(wv[0], 1), r);
  r = fmaf(blo(h0[1]), sb2f(wv[0], 2), r); r = fmaf(bhi(h0[1]), sb2f(wv[0], 3), r);
  r = fmaf(blo(h0[2]), sb2f(wv[1], 0), r); r = fmaf(bhi(h0[2]), sb2f(wv[1], 1), r);
  r = fmaf(blo(h0[3]), sb2f(wv[1], 2), r); r = fmaf(bhi(h0[3]), sb2f(wv[1], 3), r);
  r = fmaf(blo(h1[0]), sb2f(wv[2], 0), r); r = fmaf(bhi(h1[0]), sb2f(wv[2], 1), r);
  r = fmaf(blo(h1[1]), sb2f(wv[2], 2), r); r = fmaf(bhi(h1[1]), sb2f(wv[2], 3), r);
  r = fmaf(blo(h1[2]), sb2f(wv[3], 0), r); r = fmaf(bhi(h1[2]), sb2f(wv[3], 1), r);
  r = fmaf(blo(h1[3]), sb2f(wv[3], 2), r); r = fmaf(bhi(h1[3]), sb2f(wv[3], 3), r);
  return r;
}

#define GET4(v, idx) ((idx) == 0 ? (v).x : (idx) == 1 ? (v).y : (idx) == 2 ? (v).z : (v).w)

__global__ __launch_bounds__(256) void msg_i8_kernel(
    const unsigned short* __restrict__ hdb,
    const unsigned char* __restrict__ W, const unsigned short* __restrict__ S,
    const int* __restrict__ idxn, const int* __restrict__ edst,
    float* __restrict__ agg) {
  int t = blockIdx.x * 256 + threadIdx.x;
  if (t >= NE / 2) return;
  const int g = t >> 4, d = t & 15;
  const int e0 = g * 32;

  int4 dv[8], sv[8];
  const int4* dp4 = reinterpret_cast<const int4*>(edst + e0);
  const int4* sp4 = reinterpret_cast<const int4*>(idxn + e0);
#pragma unroll
  for (int i = 0; i < 8; ++i) { dv[i] = dp4[i]; sv[i] = sp4[i]; }
  uint32x4 scv[4];
  const uint32x4* scp = reinterpret_cast<const uint32x4*>(S + e0);
#pragma unroll
  for (int i = 0; i < 4; ++i) scv[i] = scp[i];

  int curA = -1, curB = -1;
  float accA = 0.0f, accB = 0.0f;
#pragma unroll
  for (int s = 0; s < 16; ++s) {
    const int q = s >> 2, r4 = s & 3;
    int dstA = GET4(dv[q], r4),     srcA = GET4(sv[q], r4);
    int dstB = GET4(dv[4 + q], r4), srcB = GET4(sv[4 + q], r4);
    int eA = e0 + s, eB = e0 + 16 + s;
    const uint32x4* hpA = reinterpret_cast<const uint32x4*>(hdb + (size_t)srcA * 16);
    const uint32x4* hpB = reinterpret_cast<const uint32x4*>(hdb + (size_t)srcB * 16);
    uint32x4 ha0 = hpA[0], ha1 = hpA[1];
    uint32x4 hb0 = hpB[0], hb1 = hpB[1];
    uint32x4 wvA = *reinterpret_cast<const uint32x4*>(W + ((size_t)eA << 8) + (d << 4));
    uint32x4 wvB = *reinterpret_cast<const uint32x4*>(W + ((size_t)eB << 8) + (d << 4));
    uint32 swA = scv[s >> 3][(s >> 1) & 3];
    uint32 swB = scv[2 + (s >> 3)][(s >> 1) & 3];
    float scA = bf2f((unsigned short)((s & 1) ? (swA >> 16) : (swA & 0xFFFF)));
    float scB = bf2f((unsigned short)((s & 1) ? (swB >> 16) : (swB & 0xFFFF)));
    if (dstA != curA) {
      if (curA >= 0) atomicAdd(&agg[(size_t)curA * 16 + d], accA);
      curA = dstA; accA = 0.0f;
    }
    if (dstB != curB) {
      if (curB >= 0) atomicAdd(&agg[(size_t)curB * 16 + d], accB);
      curB = dstB; accB = 0.0f;
    }
    accA = fmaf(edge_dot_i8bf(ha0, ha1, wvA), scA, accA);
    accB = fmaf(edge_dot_i8bf(hb0, hb1, wvB), scB, accB);
  }
  atomicAdd(&agg[(size_t)curA * 16 + d], accA);
  atomicAdd(&agg[(size_t)curB * 16 + d], accB);
}

// ---------- GRU cell: 16 lanes per node; re-zeroes agg for the next step ----------
__global__ __launch_bounds__(256) void cell_kernel(
    float* agg, const float* __restrict__ invd,
    const float* hin, int hin_ld,
    const float* __restrict__ wih, const float* __restrict__ whh,
    const float* __restrict__ bih, const float* __restrict__ bhh,
    float* hout, int hout_ld,
    const float* sprev, int sprev_ld,
    float* sout, int sout_ld,
    unsigned short* hdn) {
  int t = blockIdx.x * 256 + threadIdx.x;
  int n = t >> 4, j = t & 15;
  if (n >= NN) return;
  float inv = invd[n];
  float x[16], h[16];
  const float4* ap = reinterpret_cast<const float4*>(agg + (size_t)n * 16);
  const float4* hp = reinterpret_cast<const float4*>(hin + (size_t)n * hin_ld);
#pragma unroll
  for (int q = 0; q < 4; ++q) {
    float4 a = ap[q];
    x[4 * q + 0] = a.x * inv; x[4 * q + 1] = a.y * inv;
    x[4 * q + 2] = a.z * inv; x[4 * q + 3] = a.w * inv;
    float4 hv4 = hp[q];
    h[4 * q + 0] = hv4.x; h[4 * q + 1] = hv4.y;
    h[4 * q + 2] = hv4.z; h[4 * q + 3] = hv4.w;
  }
  const float4* wr4 = reinterpret_cast<const float4*>(wih + j * 16);
  const float4* wz4 = reinterpret_cast<const float4*>(wih + (16 + j) * 16);
  const float4* wn4 = reinterpret_cast<const float4*>(wih + (32 + j) * 16);
  const float4* vr4 = reinterpret_cast<const float4*>(whh + j * 16);
  const float4* vz4 = reinterpret_cast<const float4*>(whh + (16 + j) * 16);
  const float4* vn4 = reinterpret_cast<const float4*>(whh + (32 + j) * 16);
  float gr = bih[j], gz = bih[16 + j], gn = bih[32 + j];
  float hr = bhh[j], hz = bhh[16 + j], hn = bhh[32 + j];
#pragma unroll
  for (int q = 0; q < 4; ++q) {
    float4 wr = wr4[q], wz = wz4[q], wn = wn4[q];
    float4 vr = vr4[q], vz = vz4[q], vn = vn4[q];
    gr = fmaf(x[4 * q + 0], wr.x, gr); gr = fmaf(x[4 * q + 1], wr.y, gr);
    gr = fmaf(x[4 * q + 2], wr.z, gr); gr = fmaf(x[4 * q + 3], wr.w, gr);
    gz = fmaf(x[4 * q + 0], wz.x, gz); gz = fmaf(x[4 * q + 1], wz.y, gz);
    gz = fmaf(x[4 * q + 2], wz.z, gz); gz = fmaf(x[4 * q + 3], wz.w, gz);
    gn = fmaf(x[4 * q + 0], wn.x, gn); gn = fmaf(x[4 * q + 1], wn.y, gn);
    gn = fmaf(x[4 * q + 2], wn.z, gn); gn = fmaf(x[4 * q + 3], wn.w, gn);
    hr = fmaf(h[4 * q + 0], vr.x, hr); hr = fmaf(h[4 * q + 1], vr.y, hr);
    hr = fmaf(h[4 * q + 2], vr.z, hr); hr = fmaf(h[4 * q + 3], vr.w, hr);
    hz = fmaf(h[4 * q + 0], vz.x, hz); hz = fmaf(h[4 * q + 1], vz.y, hz);
    hz = fmaf(h[4 * q + 2], vz.z, hz); hz = fmaf(h[4 * q + 3], vz.w, hz);
    hn = fmaf(h[4 * q + 0], vn.x, hn); hn = fmaf(h[4 * q + 1], vn.y, hn);
    hn = fmaf(h[4 * q + 2], vn.z, hn); hn = fmaf(h[4 * q + 3], vn.w, hn);
  }
  float r = 1.0f / (1.0f + expf(-(gr + hr)));
  float z = 1.0f / (1.0f + expf(-(gz + hz)));
  float nng = tanhf(gn + r * hn);
  float hv = (1.0f - z) * nng + z * h[j];

  bool do_s = (sprev != nullptr);
  float sv = 0.0f;
  if (do_s) sv = hv + sprev[(size_t)n * sprev_ld + j];
  hout[(size_t)n * hout_ld + j] = hv;
  if (do_s) sout[(size_t)n * sout_ld + j] = sv;
  if (hdn != nullptr) hdn[(size_t)n * 16 + j] = (unsigned short)f2bf_rne(do_s ? sv : hv);

  asm volatile("" ::: "memory");
  agg[(size_t)n * 16 + j] = 0.0f;
}

extern "C" void kernel_launch(void* const* d_in, const int* in_sizes, int n_in,
                              void* d_out, int out_size, void* d_ws, size_t ws_size,
                              hipStream_t stream) {
  const float* hx   = (const float*)d_in[0];
  const float* ef   = (const float*)d_in[1];
  const int*   idxn = (const int*)d_in[2];
  const int*   edst = (const int*)d_in[3];
  const float* w1   = (const float*)d_in[4];
  const float* b1   = (const float*)d_in[5];
  const float* w2   = (const float*)d_in[6];
  const float* b2   = (const float*)d_in[7];
  const float* wih  = (const float*)d_in[8];
  const float* whh  = (const float*)d_in[9];
  const float* bih  = (const float*)d_in[10];
  const float* bhh  = (const float*)d_in[11];
  float* out = (float*)d_out;

  // workspace: invd | agg | w2f/w2t | hdb (bf16 dense h) | W | S
  const size_t INV_OFF = 0;
  const size_t AGG_OFF = 200064;
  const size_t W2T_OFF = 3400192;
  const size_t HD_OFF  = W2T_OFF + 1048576;
  const size_t W_OFF   = HD_OFF + (size_t)NN * 32;
  if (ws_size < W_OFF + 1600 * 512) return;
  char* wsb = (char*)d_ws;
  float* invd = (float*)(wsb + INV_OFF);
  float* agg  = (float*)(wsb + AGG_OFF);
  float* w2t  = (float*)(wsb + W2T_OFF);
  unsigned short* w2f = (unsigned short*)(wsb + W2T_OFF);
  unsigned short* hdb = (unsigned short*)(wsb + HD_OFF);
  unsigned short* W16 = (unsigned short*)(wsb + W_OFF);
  unsigned char*  W8  = (unsigned char*)(wsb + W_OFF);
  unsigned short* S16 = (unsigned short*)(wsb + W_OFF + (size_t)NE * 256);
  size_t wrem = ws_size - W_OFF;

  int plan;       // 1 = int8 + MFMA fnet, 2 = chunked bf16
  size_t chunk = NE;
  if (wrem >= (size_t)NE * 260) plan = 1;
  else {
    plan = 2;
    chunk = (wrem / 512) & ~(size_t)15;
    if (chunk > NE) chunk = NE;
  }

  const int NB  = (NN + 255) / 256;
  const int EB  = (NE + 255) / 256;
  const int MB  = (NE / 2 + 255) / 256;
  const int CB  = (NN * 16 + 255) / 256;

  hipMemsetAsync(invd, 0, (size_t)NN * 4, stream);
  hipMemsetAsync(agg, 0, (size_t)NN * 64, stream);
  deg_count_kernel<<<EB, 256, 0, stream>>>(edst, invd);
  deg_inv_kernel<<<NB, 256, 0, stream>>>(invd);
  copy_col0_kernel<<<NB, 256, 0, stream>>>(hx, out);
  hx2hd_kernel<<<CB, 256, 0, stream>>>(hx, hdb);

  if (plan == 1) {
    repack_w2f_kernel<<<64, 256, 0, stream>>>(w2, w2f);
    fnet_mfma_i8_kernel<<<3125, 1024, 0, stream>>>(ef, w1, b1, w2f, b2, W8, S16);
  } else {
    repack_w2_kernel<<<1024, 256, 0, stream>>>(w2, w2t);
  }

  auto col = [&](int c) { return out + (size_t)c * 16; };

  auto step = [&](const float* hinF, int hin_ld, float* hout,
                  const float* sprev, float* sout, unsigned short* hdn) {
    if (plan == 1) {
      msg_i8_kernel<<<MB, 256, 0, stream>>>(hdb, W8, S16, idxn, edst, agg);
    } else {
      hipMemsetAsync(agg, 0, (size_t)NN * 64, stream);
      for (size_t e0 = 0; e0 < NE; e0 += chunk) {
        int cnt = (int)(((size_t)NE - e0) < chunk ? ((size_t)NE - e0) : chunk);
        fnet_bf16_kernel<<<(cnt + 255) / 256, 256, 0, stream>>>(ef, w1, b1, w2t, b2, W16,
                                                                (long long)e0, cnt);
        msg_bf16_kernel<<<(cnt + 255) / 256, 256, 0, stream>>>(hinF, hin_ld, W16,
                                                               (long long)e0, cnt,
                                                               idxn, edst, agg);
      }
    }
    cell_kernel<<<CB, 256, 0, stream>>>(agg, invd, hinF, hin_ld, wih, whh, bih, bhh,
                                        hout, OUTC, sprev, OUTC, sout, OUTC, hdn);
  };

  // cols 0..10 = [hx,h1,h2,s1,h4,s2,h6,s3,h8,s4,h10]; col10 = rotating stash for
  // h3/h5/h7/h9. hdb always holds the NEXT step's bf16 msg input (h or s).
  step(hx,      16,  col(1),  nullptr, nullptr, hdb);  // h1
  step(col(1), OUTC, col(2),  nullptr, nullptr, hdb);  // h2
  step(col(2), OUTC, col(10), col(1),  col(3),  hdb);  // h3 stash; s1
  step(col(3), OUTC, col(4),  nullptr, nullptr, hdb);  // h4
  step(col(4), OUTC, col(10), col(10), col(5),  hdb);  // h5 stash; s2
  step(col(5), OUTC, col(6),  nullptr, nullptr, hdb);  // h6
  step(col(6), OUTC, col(10), col(10), col(7),  hdb);  // h7 stash; s3
  step(col(7), OUTC, col(8),  nullptr, nullptr, hdb);  // h8
  step(col(8), OUTC, col(10), col(10), col(9),  hdb);  // h9 stash; s4
  step(col(9), OUTC, col(10), nullptr, nullptr, nullptr);  // h10 (final)
}

// Round 19
// 825.192 us; speedup vs baseline: 4.5374x; 1.0728x over previous
//
#include <hip/hip_runtime.h>

#define NN 50000
#define NE 800000
#define OUTC 176  // 11 * 16

typedef unsigned int uint32;
typedef short bf16x8 __attribute__((ext_vector_type(8)));
typedef float f32x4 __attribute__((ext_vector_type(4)));
typedef unsigned int uint32x4 __attribute__((ext_vector_type(4)));

// ---------- bf16 helpers (manual, RNE) ----------
__device__ __forceinline__ uint32 f2bf_rne(float f) {
  union { float f; uint32 u; } v; v.f = f;
  uint32 u = v.u;
  return (u + 0x7FFFu + ((u >> 16) & 1u)) >> 16;
}
__device__ __forceinline__ uint32 packbf2(float a, float b) {
  return f2bf_rne(a) | (f2bf_rne(b) << 16);
}
__device__ __forceinline__ float blo(uint32 u) {
  union { uint32 x; float f; } t; t.x = u << 16; return t.f;
}
__device__ __forceinline__ float bhi(uint32 u) {
  union { uint32 x; float f; } t; t.x = u & 0xFFFF0000u; return t.f;
}
__device__ __forceinline__ float bf2f(unsigned short v) {
  union { uint32 x; float f; } t; t.x = ((uint32)v) << 16; return t.f;
}
__device__ __forceinline__ float sb2f(uint32 w, int b) {
  return (float)((int)(w << (24 - 8 * b)) >> 24);
}

// ---------- small kernels ----------
__global__ __launch_bounds__(256) void deg_count_kernel(const int* __restrict__ edst,
                                                        float* __restrict__ deg) {
  int e = blockIdx.x * 256 + threadIdx.x;
  if (e < NE) atomicAdd(&deg[edst[e]], 1.0f);
}

__global__ __launch_bounds__(256) void deg_inv_kernel(float* __restrict__ deg) {
  int n = blockIdx.x * 256 + threadIdx.x;
  if (n < NN) deg[n] = 1.0f / fmaxf(deg[n], 1.0f);
}

__global__ __launch_bounds__(256) void copy_col0_kernel(const float* __restrict__ hx,
                                                        float* __restrict__ out) {
  int n = blockIdx.x * 256 + threadIdx.x;
  if (n >= NN) return;
  const float4* s = reinterpret_cast<const float4*>(hx + (size_t)n * 16);
  float4* d = reinterpret_cast<float4*>(out + (size_t)n * OUTC);
  d[0] = s[0]; d[1] = s[1]; d[2] = s[2]; d[3] = s[3];
}

__global__ __launch_bounds__(256) void hx2hd_kernel(const float* __restrict__ hx,
                                                    unsigned short* __restrict__ hdb) {
  int t = blockIdx.x * 256 + threadIdx.x;
  if (t < NN * 16) hdb[t] = (unsigned short)f2bf_rne(hx[t]);
}

__global__ __launch_bounds__(256) void repack_w2_kernel(const float* __restrict__ w2,
                                                        float* __restrict__ w2t) {
  int i = blockIdx.x * 256 + threadIdx.x;
  if (i >= 256 * 1024) return;
  int d = i >> 10, r = i & 1023, k = r >> 4, c = r & 15;
  w2t[i] = w2[k * 256 + c * 16 + d];
}

__global__ __launch_bounds__(256) void repack_w2f_kernel(const float* __restrict__ w2,
                                                         unsigned short* __restrict__ w2f) {
  int i = blockIdx.x * 256 + threadIdx.x;  // 0..16383
  if (i >= 16384) return;
  int jj = i & 7;
  int l = (i >> 3) & 63;
  int nbm = i >> 9;
  int m = nbm & 1, nb = nbm >> 1;
  int k = m * 32 + (l >> 4) * 8 + jj;
  int j = nb * 16 + (l & 15);
  w2f[i] = (unsigned short)f2bf_rne(w2[k * 256 + j]);
}

// ---------- MFMA fnet: fused layer1 + 16x256x64 GEMM + int8 quantize ----------
// R16 config (best measured): 512-thread blocks, 8 waves share one 32KB w2s.
__global__ __launch_bounds__(512) void fnet_mfma_i8_kernel(
    const float* __restrict__ ef, const float* __restrict__ w1, const float* __restrict__ b1,
    const unsigned short* __restrict__ w2f, const float* __restrict__ b2,
    unsigned char* __restrict__ W, unsigned short* __restrict__ S) {
  __shared__ float efs[1664];         // 128 edges x 13 feats
  __shared__ short w2s[16384];        // full B fragments, 32KB
  const int wave = threadIdx.x >> 6;  // 0..7
  const int l = threadIdx.x & 63;
  const int wid = blockIdx.x * 8 + wave;
  const int d = l & 15, kg = l >> 4;

#pragma unroll
  for (int i = 0; i < 4; ++i)
    reinterpret_cast<uint4*>(w2s)[threadIdx.x + 512 * i] =
        reinterpret_cast<const uint4*>(w2f)[threadIdx.x + 512 * i];
  long long E0 = (long long)blockIdx.x * 128;
  if (threadIdx.x < 416) {
    reinterpret_cast<float4*>(efs)[threadIdx.x] =
        reinterpret_cast<const float4*>(ef + E0 * 13)[threadIdx.x];
  }
  __syncthreads();

  const int eloc = wave * 16 + d;
  float f[13];
#pragma unroll
  for (int i = 0; i < 13; ++i) f[i] = efs[eloc * 13 + i];
  float ua[8], ub[8];
#pragma unroll
  for (int j = 0; j < 8; ++j) { ua[j] = b1[kg * 8 + j]; ub[j] = b1[32 + kg * 8 + j]; }
#pragma unroll
  for (int i = 0; i < 13; ++i) {
    const float4* wa = reinterpret_cast<const float4*>(w1 + i * 64 + kg * 8);
    const float4* wb = reinterpret_cast<const float4*>(w1 + i * 64 + 32 + kg * 8);
    float4 a0 = wa[0], a1 = wa[1], c0 = wb[0], c1 = wb[1];
    float fi = f[i];
    ua[0] = fmaf(fi, a0.x, ua[0]); ua[1] = fmaf(fi, a0.y, ua[1]);
    ua[2] = fmaf(fi, a0.z, ua[2]); ua[3] = fmaf(fi, a0.w, ua[3]);
    ua[4] = fmaf(fi, a1.x, ua[4]); ua[5] = fmaf(fi, a1.y, ua[5]);
    ua[6] = fmaf(fi, a1.z, ua[6]); ua[7] = fmaf(fi, a1.w, ua[7]);
    ub[0] = fmaf(fi, c0.x, ub[0]); ub[1] = fmaf(fi, c0.y, ub[1]);
    ub[2] = fmaf(fi, c0.z, ub[2]); ub[3] = fmaf(fi, c0.w, ub[3]);
    ub[4] = fmaf(fi, c1.x, ub[4]); ub[5] = fmaf(fi, c1.y, ub[5]);
    ub[6] = fmaf(fi, c1.z, ub[6]); ub[7] = fmaf(fi, c1.w, ub[7]);
  }
  bf16x8 afrag0, afrag1;
#pragma unroll
  for (int j = 0; j < 8; ++j) {
    afrag0[j] = (short)f2bf_rne(fmaxf(ua[j], 0.0f));
    afrag1[j] = (short)f2bf_rne(fmaxf(ub[j], 0.0f));
  }

  float bias[16];
#pragma unroll
  for (int nb = 0; nb < 16; ++nb) bias[nb] = b2[nb * 16 + d];

  const bf16x8* Bp = reinterpret_cast<const bf16x8*>(w2s);
  f32x4 acc[16];
#pragma unroll
  for (int nb = 0; nb < 16; ++nb) {
    f32x4 c; c[0] = bias[nb]; c[1] = bias[nb]; c[2] = bias[nb]; c[3] = bias[nb];
    bf16x8 bf0 = Bp[(nb * 2 + 0) * 64 + l];
    bf16x8 bf1 = Bp[(nb * 2 + 1) * 64 + l];
    c = __builtin_amdgcn_mfma_f32_16x16x32_bf16(afrag0, bf0, c, 0, 0, 0);
    c = __builtin_amdgcn_mfma_f32_16x16x32_bf16(afrag1, bf1, c, 0, 0, 0);
    acc[nb] = c;
  }

  float mx[4];
#pragma unroll
  for (int r = 0; r < 4; ++r) {
    float m = 0.0f;
#pragma unroll
    for (int c = 0; c < 16; ++c) m = fmaxf(m, fabsf(acc[c][r]));
    mx[r] = m;
  }
#pragma unroll
  for (int mask = 1; mask < 16; mask <<= 1) {
#pragma unroll
    for (int r = 0; r < 4; ++r) mx[r] = fmaxf(mx[r], __shfl_xor(mx[r], mask));
  }
  uint32 sb[4]; float sinv[4];
#pragma unroll
  for (int r = 0; r < 4; ++r) {
    sb[r] = f2bf_rne(mx[r] * (1.0f / 127.0f));
    float sd = bf2f((unsigned short)sb[r]);
    sinv[r] = (sd > 0.0f) ? (1.0f / sd) : 0.0f;
  }
  if (d == 0) {
    uint32 lo = sb[0] | (sb[1] << 16), hi = sb[2] | (sb[3] << 16);
    *reinterpret_cast<uint2*>(S + (size_t)wid * 16 + kg * 4) = make_uint2(lo, hi);
  }

#pragma unroll
  for (int r = 0; r < 4; ++r) {
    size_t er = (size_t)wid * 16 + kg * 4 + r;
    uint32 p[4];
#pragma unroll
    for (int q = 0; q < 4; ++q) {
      uint32 wv = 0;
#pragma unroll
      for (int b = 0; b < 4; ++b) {
        float qf = fminf(127.0f, fmaxf(-127.0f, rintf(acc[q * 4 + b][r] * sinv[r])));
        wv |= ((uint32)((int)qf & 255)) << (8 * b);
      }
      p[q] = wv;
    }
    *reinterpret_cast<uint4*>(W + (er << 8) + (d << 4)) = make_uint4(p[0], p[1], p[2], p[3]);
  }
}

// ---------- chunked-bf16 fallback fnet (plan 2) ----------
__device__ __forceinline__ void fnet_layer1(const float* __restrict__ ef, long long e,
                                            const float* __restrict__ w1,
                                            const float* __restrict__ b1,
                                            float* u) {
  float f[13];
#pragma unroll
  for (int i = 0; i < 13; ++i) f[i] = ef[(size_t)e * 13 + i];
#pragma unroll
  for (int k = 0; k < 64; ++k) u[k] = b1[k];
#pragma unroll
  for (int i = 0; i < 13; ++i) {
    float fi = f[i];
#pragma unroll
    for (int k = 0; k < 64; ++k) u[k] = fmaf(fi, w1[i * 64 + k], u[k]);
  }
#pragma unroll
  for (int k = 0; k < 64; ++k) u[k] = fmaxf(u[k], 0.0f);
}

__global__ __launch_bounds__(256) void fnet_bf16_kernel(
    const float* __restrict__ ef, const float* __restrict__ w1, const float* __restrict__ b1,
    const float* __restrict__ w2t, const float* __restrict__ b2,
    unsigned short* __restrict__ W, long long ebase, int ecnt) {
  int t = blockIdx.x * 256 + threadIdx.x;
  if (t >= ecnt) return;
  float u[64];
  fnet_layer1(ef, ebase + t, w1, b1, u);
#pragma unroll 1
  for (int dt = 0; dt < 8; ++dt) {
    uint32 p[16];
#pragma unroll
    for (int dd = 0; dd < 2; ++dd) {
      const int d = dt * 2 + dd;
      const float* wr = w2t + ((size_t)d << 10);
      float acc[16];
#pragma unroll
      for (int c = 0; c < 16; ++c) acc[c] = b2[c * 16 + d];
#pragma unroll
      for (int k = 0; k < 64; ++k) {
        float uk = u[k];
#pragma unroll
        for (int c = 0; c < 16; ++c) acc[c] = fmaf(uk, wr[k * 16 + c], acc[c]);
      }
#pragma unroll
      for (int q = 0; q < 8; ++q) p[dd * 8 + q] = packbf2(acc[2 * q], acc[2 * q + 1]);
    }
    uint4* dp = reinterpret_cast<uint4*>(W + ((size_t)t << 8) + (dt << 5));
    dp[0] = make_uint4(p[0], p[1], p[2], p[3]);
    dp[1] = make_uint4(p[4], p[5], p[6], p[7]);
    dp[2] = make_uint4(p[8], p[9], p[10], p[11]);
    dp[3] = make_uint4(p[12], p[13], p[14], p[15]);
  }
}

__global__ __launch_bounds__(256) void msg_bf16_kernel(
    const float* __restrict__ h, int h_ld,
    const unsigned short* __restrict__ W, long long ebase, int ecnt,
    const int* __restrict__ idxn, const int* __restrict__ edst,
    float* __restrict__ agg) {
  int t = blockIdx.x * 256 + threadIdx.x;
  if (t >= ecnt) return;
  int g = t >> 4, d = t & 15;
  int cur = -1;
  float acc = 0.0f;
  for (int s = 0; s < 16; ++s) {
    int erel = g * 16 + s;
    long long e = ebase + erel;
    int dst = edst[e];
    if (dst != cur) {
      if (cur >= 0) atomicAdd(&agg[(size_t)cur * 16 + d], acc);
      cur = dst; acc = 0.0f;
    }
    int src = idxn[e];
    const float4* hp = reinterpret_cast<const float4*>(h + (size_t)src * h_ld);
    float4 a0 = hp[0], a1 = hp[1], a2 = hp[2], a3 = hp[3];
    const uint4* wp = reinterpret_cast<const uint4*>(W + ((size_t)erel << 8) + (d << 4));
    uint4 w0 = wp[0], w1 = wp[1];
    acc = fmaf(a0.x, blo(w0.x), acc); acc = fmaf(a0.y, bhi(w0.x), acc);
    acc = fmaf(a0.z, blo(w0.y), acc); acc = fmaf(a0.w, bhi(w0.y), acc);
    acc = fmaf(a1.x, blo(w0.z), acc); acc = fmaf(a1.y, bhi(w0.z), acc);
    acc = fmaf(a1.z, blo(w0.w), acc); acc = fmaf(a1.w, bhi(w0.w), acc);
    acc = fmaf(a2.x, blo(w1.x), acc); acc = fmaf(a2.y, bhi(w1.x), acc);
    acc = fmaf(a2.z, blo(w1.y), acc); acc = fmaf(a2.w, bhi(w1.y), acc);
    acc = fmaf(a3.x, blo(w1.z), acc); acc = fmaf(a3.y, bhi(w1.z), acc);
    acc = fmaf(a3.z, blo(w1.w), acc); acc = fmaf(a3.w, bhi(w1.w), acc);
  }
  if (cur >= 0) atomicAdd(&agg[(size_t)cur * 16 + d], acc);
}

// int8 W x bf16 h (L2-resident hdb). 16 lanes per 32-edge group (2 strips).
// 64-thread blocks: 1 wave/block so waves retire independently (R12-R16 msg
// showed ~30% time-avg occupancy -> ramp/tail skew with 4-wave blocks).
__device__ __forceinline__ float edge_dot_i8bf(const uint32x4& h0, const uint32x4& h1,
                                               const uint32x4& wv) {
  float r = 0.0f;
  r = fmaf(blo(h0[0]), sb2f(wv[0], 0), r); r = fmaf(bhi(h0[0]), sb2f(wv[0], 1), r);
  r = fmaf(blo(h0[1]), sb2f(wv[0], 2), r); r = fmaf(bhi(h0[1]), sb2f(wv[0], 3), r);
  r = fmaf(blo(h0[2]), sb2f(wv[1], 0), r); r = fmaf(bhi(h0[2]), sb2f(wv[1], 1), r);
  r = fmaf(blo(h0[3]), sb2f(wv[1], 2), r); r = fmaf(bhi(h0[3]), sb2f(wv[1], 3), r);
  r = fmaf(blo(h1[0]), sb2f(wv[2], 0), r); r = fmaf(bhi(h1[0]), sb2f(wv[2], 1), r);
  r = fmaf(blo(h1[1]), sb2f(wv[2], 2), r); r = fmaf(bhi(h1[1]), sb2f(wv[2], 3), r);
  r = fmaf(blo(h1[2]), sb2f(wv[3], 0), r); r = fmaf(bhi(h1[2]), sb2f(wv[3], 1), r);
  r = fmaf(blo(h1[3]), sb2f(wv[3], 2), r); r = fmaf(bhi(h1[3]), sb2f(wv[3], 3), r);
  return r;
}

#define GET4(v, idx) ((idx) == 0 ? (v).x : (idx) == 1 ? (v).y : (idx) == 2 ? (v).z : (v).w)

__global__ __launch_bounds__(64) void msg_i8_kernel(
    const unsigned short* __restrict__ hdb,
    const unsigned char* __restrict__ W, const unsigned short* __restrict__ S,
    const int* __restrict__ idxn, const int* __restrict__ edst,
    float* __restrict__ agg) {
  int t = blockIdx.x * 64 + threadIdx.x;
  if (t >= NE / 2) return;
  const int g = t >> 4, d = t & 15;
  const int e0 = g * 32;

  int4 dv[8], sv[8];
  const int4* dp4 = reinterpret_cast<const int4*>(edst + e0);
  const int4* sp4 = reinterpret_cast<const int4*>(idxn + e0);
#pragma unroll
  for (int i = 0; i < 8; ++i) { dv[i] = dp4[i]; sv[i] = sp4[i]; }
  uint32x4 scv[4];
  const uint32x4* scp = reinterpret_cast<const uint32x4*>(S + e0);
#pragma unroll
  for (int i = 0; i < 4; ++i) scv[i] = scp[i];

  int curA = -1, curB = -1;
  float accA = 0.0f, accB = 0.0f;
#pragma unroll
  for (int s = 0; s < 16; ++s) {
    const int q = s >> 2, r4 = s & 3;
    int dstA = GET4(dv[q], r4),     srcA = GET4(sv[q], r4);
    int dstB = GET4(dv[4 + q], r4), srcB = GET4(sv[4 + q], r4);
    int eA = e0 + s, eB = e0 + 16 + s;
    const uint32x4* hpA = reinterpret_cast<const uint32x4*>(hdb + (size_t)srcA * 16);
    const uint32x4* hpB = reinterpret_cast<const uint32x4*>(hdb + (size_t)srcB * 16);
    uint32x4 ha0 = hpA[0], ha1 = hpA[1];
    uint32x4 hb0 = hpB[0], hb1 = hpB[1];
    uint32x4 wvA = *reinterpret_cast<const uint32x4*>(W + ((size_t)eA << 8) + (d << 4));
    uint32x4 wvB = *reinterpret_cast<const uint32x4*>(W + ((size_t)eB << 8) + (d << 4));
    uint32 swA = scv[s >> 3][(s >> 1) & 3];
    uint32 swB = scv[2 + (s >> 3)][(s >> 1) & 3];
    float scA = bf2f((unsigned short)((s & 1) ? (swA >> 16) : (swA & 0xFFFF)));
    float scB = bf2f((unsigned short)((s & 1) ? (swB >> 16) : (swB & 0xFFFF)));
    if (dstA != curA) {
      if (curA >= 0) atomicAdd(&agg[(size_t)curA * 16 + d], accA);
      curA = dstA; accA = 0.0f;
    }
    if (dstB != curB) {
      if (curB >= 0) atomicAdd(&agg[(size_t)curB * 16 + d], accB);
      curB = dstB; accB = 0.0f;
    }
    accA = fmaf(edge_dot_i8bf(ha0, ha1, wvA), scA, accA);
    accB = fmaf(edge_dot_i8bf(hb0, hb1, wvB), scB, accB);
  }
  atomicAdd(&agg[(size_t)curA * 16 + d], accA);
  atomicAdd(&agg[(size_t)curB * 16 + d], accB);
}

// ---------- GRU cell: 16 lanes per node; re-zeroes agg for the next step ----------
__global__ __launch_bounds__(256) void cell_kernel(
    float* agg, const float* __restrict__ invd,
    const float* hin, int hin_ld,
    const float* __restrict__ wih, const float* __restrict__ whh,
    const float* __restrict__ bih, const float* __restrict__ bhh,
    float* hout, int hout_ld,
    const float* sprev, int sprev_ld,
    float* sout, int sout_ld,
    unsigned short* hdn) {
  int t = blockIdx.x * 256 + threadIdx.x;
  int n = t >> 4, j = t & 15;
  if (n >= NN) return;
  float inv = invd[n];
  float x[16], h[16];
  const float4* ap = reinterpret_cast<const float4*>(agg + (size_t)n * 16);
  const float4* hp = reinterpret_cast<const float4*>(hin + (size_t)n * hin_ld);
#pragma unroll
  for (int q = 0; q < 4; ++q) {
    float4 a = ap[q];
    x[4 * q + 0] = a.x * inv; x[4 * q + 1] = a.y * inv;
    x[4 * q + 2] = a.z * inv; x[4 * q + 3] = a.w * inv;
    float4 hv4 = hp[q];
    h[4 * q + 0] = hv4.x; h[4 * q + 1] = hv4.y;
    h[4 * q + 2] = hv4.z; h[4 * q + 3] = hv4.w;
  }
  const float4* wr4 = reinterpret_cast<const float4*>(wih + j * 16);
  const float4* wz4 = reinterpret_cast<const float4*>(wih + (16 + j) * 16);
  const float4* wn4 = reinterpret_cast<const float4*>(wih + (32 + j) * 16);
  const float4* vr4 = reinterpret_cast<const float4*>(whh + j * 16);
  const float4* vz4 = reinterpret_cast<const float4*>(whh + (16 + j) * 16);
  const float4* vn4 = reinterpret_cast<const float4*>(whh + (32 + j) * 16);
  float gr = bih[j], gz = bih[16 + j], gn = bih[32 + j];
  float hr = bhh[j], hz = bhh[16 + j], hn = bhh[32 + j];
#pragma unroll
  for (int q = 0; q < 4; ++q) {
    float4 wr = wr4[q], wz = wz4[q], wn = wn4[q];
    float4 vr = vr4[q], vz = vz4[q], vn = vn4[q];
    gr = fmaf(x[4 * q + 0], wr.x, gr); gr = fmaf(x[4 * q + 1], wr.y, gr);
    gr = fmaf(x[4 * q + 2], wr.z, gr); gr = fmaf(x[4 * q + 3], wr.w, gr);
    gz = fmaf(x[4 * q + 0], wz.x, gz); gz = fmaf(x[4 * q + 1], wz.y, gz);
    gz = fmaf(x[4 * q + 2], wz.z, gz); gz = fmaf(x[4 * q + 3], wz.w, gz);
    gn = fmaf(x[4 * q + 0], wn.x, gn); gn = fmaf(x[4 * q + 1], wn.y, gn);
    gn = fmaf(x[4 * q + 2], wn.z, gn); gn = fmaf(x[4 * q + 3], wn.w, gn);
    hr = fmaf(h[4 * q + 0], vr.x, hr); hr = fmaf(h[4 * q + 1], vr.y, hr);
    hr = fmaf(h[4 * q + 2], vr.z, hr); hr = fmaf(h[4 * q + 3], vr.w, hr);
    hz = fmaf(h[4 * q + 0], vz.x, hz); hz = fmaf(h[4 * q + 1], vz.y, hz);
    hz = fmaf(h[4 * q + 2], vz.z, hz); hz = fmaf(h[4 * q + 3], vz.w, hz);
    hn = fmaf(h[4 * q + 0], vn.x, hn); hn = fmaf(h[4 * q + 1], vn.y, hn);
    hn = fmaf(h[4 * q + 2], vn.z, hn); hn = fmaf(h[4 * q + 3], vn.w, hn);
  }
  float r = 1.0f / (1.0f + expf(-(gr + hr)));
  float z = 1.0f / (1.0f + expf(-(gz + hz)));
  float nng = tanhf(gn + r * hn);
  float hv = (1.0f - z) * nng + z * h[j];

  bool do_s = (sprev != nullptr);
  float sv = 0.0f;
  if (do_s) sv = hv + sprev[(size_t)n * sprev_ld + j];
  hout[(size_t)n * hout_ld + j] = hv;
  if (do_s) sout[(size_t)n * sout_ld + j] = sv;
  if (hdn != nullptr) hdn[(size_t)n * 16 + j] = (unsigned short)f2bf_rne(do_s ? sv : hv);

  asm volatile("" ::: "memory");
  agg[(size_t)n * 16 + j] = 0.0f;
}

extern "C" void kernel_launch(void* const* d_in, const int* in_sizes, int n_in,
                              void* d_out, int out_size, void* d_ws, size_t ws_size,
                              hipStream_t stream) {
  const float* hx   = (const float*)d_in[0];
  const float* ef   = (const float*)d_in[1];
  const int*   idxn = (const int*)d_in[2];
  const int*   edst = (const int*)d_in[3];
  const float* w1   = (const float*)d_in[4];
  const float* b1   = (const float*)d_in[5];
  const float* w2   = (const float*)d_in[6];
  const float* b2   = (const float*)d_in[7];
  const float* wih  = (const float*)d_in[8];
  const float* whh  = (const float*)d_in[9];
  const float* bih  = (const float*)d_in[10];
  const float* bhh  = (const float*)d_in[11];
  float* out = (float*)d_out;

  // workspace: invd | agg | w2f/w2t | hdb (bf16 dense h) | W | S
  const size_t INV_OFF = 0;
  const size_t AGG_OFF = 200064;
  const size_t W2T_OFF = 3400192;
  const size_t HD_OFF  = W2T_OFF + 1048576;
  const size_t W_OFF   = HD_OFF + (size_t)NN * 32;
  if (ws_size < W_OFF + 1600 * 512) return;
  char* wsb = (char*)d_ws;
  float* invd = (float*)(wsb + INV_OFF);
  float* agg  = (float*)(wsb + AGG_OFF);
  float* w2t  = (float*)(wsb + W2T_OFF);
  unsigned short* w2f = (unsigned short*)(wsb + W2T_OFF);
  unsigned short* hdb = (unsigned short*)(wsb + HD_OFF);
  unsigned short* W16 = (unsigned short*)(wsb + W_OFF);
  unsigned char*  W8  = (unsigned char*)(wsb + W_OFF);
  unsigned short* S16 = (unsigned short*)(wsb + W_OFF + (size_t)NE * 256);
  size_t wrem = ws_size - W_OFF;

  int plan;       // 1 = int8 + MFMA fnet, 2 = chunked bf16
  size_t chunk = NE;
  if (wrem >= (size_t)NE * 260) plan = 1;
  else {
    plan = 2;
    chunk = (wrem / 512) & ~(size_t)15;
    if (chunk > NE) chunk = NE;
  }

  const int NB  = (NN + 255) / 256;
  const int EB  = (NE + 255) / 256;
  const int MB64 = (NE / 2 + 63) / 64;    // msg: 64-thread blocks
  const int CB  = (NN * 16 + 255) / 256;  // cell: 16 lanes/node

  hipMemsetAsync(invd, 0, (size_t)NN * 4, stream);
  hipMemsetAsync(agg, 0, (size_t)NN * 64, stream);
  deg_count_kernel<<<EB, 256, 0, stream>>>(edst, invd);
  deg_inv_kernel<<<NB, 256, 0, stream>>>(invd);
  copy_col0_kernel<<<NB, 256, 0, stream>>>(hx, out);
  hx2hd_kernel<<<CB, 256, 0, stream>>>(hx, hdb);

  if (plan == 1) {
    repack_w2f_kernel<<<64, 256, 0, stream>>>(w2, w2f);
    fnet_mfma_i8_kernel<<<6250, 512, 0, stream>>>(ef, w1, b1, w2f, b2, W8, S16);
  } else {
    repack_w2_kernel<<<1024, 256, 0, stream>>>(w2, w2t);
  }

  auto col = [&](int c) { return out + (size_t)c * 16; };

  auto step = [&](const float* hinF, int hin_ld, float* hout,
                  const float* sprev, float* sout, unsigned short* hdn) {
    if (plan == 1) {
      msg_i8_kernel<<<MB64, 64, 0, stream>>>(hdb, W8, S16, idxn, edst, agg);
    } else {
      hipMemsetAsync(agg, 0, (size_t)NN * 64, stream);
      for (size_t e0 = 0; e0 < NE; e0 += chunk) {
        int cnt = (int)(((size_t)NE - e0) < chunk ? ((size_t)NE - e0) : chunk);
        fnet_bf16_kernel<<<(cnt + 255) / 256, 256, 0, stream>>>(ef, w1, b1, w2t, b2, W16,
                                                                (long long)e0, cnt);
        msg_bf16_kernel<<<(cnt + 255) / 256, 256, 0, stream>>>(hinF, hin_ld, W16,
                                                               (long long)e0, cnt,
                                                               idxn, edst, agg);
      }
    }
    cell_kernel<<<CB, 256, 0, stream>>>(agg, invd, hinF, hin_ld, wih, whh, bih, bhh,
                                        hout, OUTC, sprev, OUTC, sout, OUTC, hdn);
  };

  // cols 0..10 = [hx,h1,h2,s1,h4,s2,h6,s3,h8,s4,h10]; col10 = rotating stash for
  // h3/h5/h7/h9. hdb always holds the NEXT step's bf16 msg input (h or s).
  step(hx,      16,  col(1),  nullptr, nullptr, hdb);  // h1
  step(col(1), OUTC, col(2),  nullptr, nullptr, hdb);  // h2
  step(col(2), OUTC, col(10), col(1),  col(3),  hdb);  // h3 stash; s1
  step(col(3), OUTC, col(4),  nullptr, nullptr, hdb);  // h4
  step(col(4), OUTC, col(10), col(10), col(5),  hdb);  // h5 stash; s2
  step(col(5), OUTC, col(6),  nullptr, nullptr, hdb);  // h6
  step(col(6), OUTC, col(10), col(10), col(7),  hdb);  // h7 stash; s3
  step(col(7), OUTC, col(8),  nullptr, nullptr, hdb);  // h8
  step(col(8), OUTC, col(10), col(10), col(9),  hdb);  // h9 stash; s4
  step(col(9), OUTC, col(10), nullptr, nullptr, nullptr);  // h10 (final)
}